// Round 2
// baseline (177.528 us; speedup 1.0000x reference)
//
#include <hip/hip_runtime.h>

// PureMul32 circuit, algebraically collapsed.
//
// Per token (b,p), with constants a=x[OPMUL], na=x[NIB_A], nb=x[NIB_B],
// ci=x[CARRY_IN], p=position:
//   r0   = x[RESULT]*(1-a)
//   t   += nb * 1.875 * (p+1)^2 / 2                      (TEMP, never read back)
//   for i in 0..31:  npos=i/4, bit=i%4
//     r += (ci + 2^bit*na) * ((p>=npos) ? (p-npos+1)^2/2 : 0)
//     f  = staircase(r) = sum_{k=1..15} clamp(r-16k+1,0,1)   [closed form]
//     r -= 16*a*f ;  co += a*f
// All other channels pass through unchanged.
//
// v2: LDS-staged I/O -> every global access lane-contiguous (fixed v1's
//     32-lines-per-instruction scatter + partial-line stores, WRITE 98->66MB).
// v3: (a) nontemporal output stores: output is never re-read in-dispatch;
//     bypassing L2/L3 stops the 64MB write stream from evicting the
//     L3-resident input (round-0 FETCH was 33MB for a 64MB input = L3 was
//     absorbing re-reads; protect that).
//     (b) half the LDS round-trip eliminated: slot = tid&3 is loop-invariant,
//     so lanes owning slots 2/3 (channels 8-15, pass-through except the OPMUL
//     scalar) keep their data in registers; only slots 0/1 + a compact
//     opmul[256] array are staged. Staging stride = 3 float4 (12 words) ->
//     bank pattern period 8 lanes, only free 2-way aliasing.

#define TOK_THREADS 256
#define TOKENS_PER_BLOCK 256  // == TOK_THREADS: one token per thread

typedef float v4f __attribute__((ext_vector_type(4)));

__device__ __forceinline__ void nt_store4(float4* p, float4 v) {
  __builtin_nontemporal_store(*reinterpret_cast<v4f*>(&v),
                              reinterpret_cast<v4f*>(p));
}

__device__ __forceinline__ void mul32_compute(float4& v0, float4& v1,
                                              float a, float p) {
  const float na = v0.y;               // NIB_A
  const float nb = v0.z;               // NIB_B
  const float ci = v1.x;               // CARRY_IN

  // FFN0: r = r*(1-a)
  float r  = fmaf(-a, v0.w, v0.w);
  float co = v1.y;
  float t  = v1.z;

  // TEMP closed form: nb * (1+1/2+1/4+1/8) * (p+1)^2/2
  t = fmaf(nb * 0.9375f, (p + 1.f) * (p + 1.f), t);

  // gate per bit: ci + 2^bit * na
  const float g0 = ci + na;
  const float g1 = fmaf(2.f, na, ci);
  const float g2 = fmaf(4.f, na, ci);
  const float g3 = fmaf(8.f, na, ci);

#pragma unroll
  for (int npos = 0; npos < 8; ++npos) {
    const float d = p - (float)npos + 1.f;       // >=1 iff p>=npos, <=0 otherwise
    const float T = (d > 0.f) ? 0.5f * d * d : 0.f;
#pragma unroll
    for (int bit = 0; bit < 4; ++bit) {
      const float g = (bit == 0) ? g0 : (bit == 1) ? g1 : (bit == 2) ? g2 : g3;
      r = fmaf(g, T, r);
      // carry staircase f(r) = sum_{k=1..15} clamp(r-16k+1,0,1), r >= 0 always
      const float c    = floorf(r * 0.0625f);
      const float full = fminf(c, 15.f);
      float ramp = fminf(fmaxf(fmaf(-16.f, c, r) - 15.f, 0.f), 1.f);
      ramp = (c < 15.f) ? ramp : 0.f;
      const float f = full + ramp;
      r  = fmaf(-16.f * a, f, r);
      co = fmaf(a, f, co);
    }
  }

  v0.w = r;
  v1.y = co;
  v1.z = t;
}

__global__ __launch_bounds__(TOK_THREADS) void pure_mul32_kernel(
    const float* __restrict__ x, float* __restrict__ out, int ntok) {
  // Slots 0,1 per token at stride 3 (pad slot) + compact OPMUL scalar array.
  __shared__ float4 stage[TOKENS_PER_BLOCK * 3];
  __shared__ float opm[TOKENS_PER_BLOCK];

  const int t = threadIdx.x;
  const int slot = t & 3;  // invariant across the 4 load/store iterations
  const int tok0 = blockIdx.x * TOKENS_PER_BLOCK;

  const float4* __restrict__ xin4 = reinterpret_cast<const float4*>(x);
  float4* __restrict__ out4 = reinterpret_cast<float4*>(out);

  if (tok0 + TOKENS_PER_BLOCK <= ntok) {
    // ---------- fast path: full block of 256 tokens ----------
    const size_t gbase = (size_t)tok0 * 4;  // float4 index of block start

    float4 keep[4];  // pass-through data held in registers by slot-2/3 lanes
#pragma unroll
    for (int j = 0; j < 4; ++j) {
      const int L = j * TOK_THREADS + t;   // contiguous 1KB per wave per j
      const float4 v = xin4[gbase + L];
      const int tk = L >> 2;               // local token 0..255
      if (slot < 2) {
        stage[tk * 3 + slot] = v;          // RESULT/CARRY half -> LDS
      } else {
        keep[j] = v;                       // pass-through half -> registers
        if (slot == 2) opm[tk] = v.z;      // OPMUL scalar (channel 10)
      }
    }
    __syncthreads();

    float4 v0 = stage[t * 3 + 0];  // {POS, NIB_A, NIB_B, RESULT}
    float4 v1 = stage[t * 3 + 1];  // {CARRY_IN, CARRY_OUT, TEMP, ch7}
    const float a = opm[t];        // OPMUL

    const float p = (float)((tok0 + t) & 7);  // POS channel = arange(P)
    mul32_compute(v0, v1, a, p);

    // Thread t's staging slots are private here; barrier only before gather.
    stage[t * 3 + 0] = v0;
    stage[t * 3 + 1] = v1;
    __syncthreads();

#pragma unroll
    for (int j = 0; j < 4; ++j) {
      const int L = j * TOK_THREADS + t;
      const int tk = L >> 2;
      const float4 v = (slot < 2) ? stage[tk * 3 + slot] : keep[j];
      nt_store4(&out4[gbase + L], v);  // coalesced, cache-bypassing
    }
  } else {
    // ---------- tail path: per-token direct (original v1 pattern) ----------
    const int idx = tok0 + t;
    if (idx >= ntok) return;

    const float4* __restrict__ xin = xin4 + (size_t)idx * 4;
    float4 v0 = xin[0];
    float4 v1 = xin[1];
    float4 v2 = xin[2];
    float4 v3 = xin[3];

    const float p = (float)(idx & 7);
    mul32_compute(v0, v1, v2.z, p);

    float4* __restrict__ o = out4 + (size_t)idx * 4;
    o[0] = v0; o[1] = v1; o[2] = v2; o[3] = v3;
  }
}

extern "C" void kernel_launch(void* const* d_in, const int* in_sizes, int n_in,
                              void* d_out, int out_size, void* d_ws, size_t ws_size,
                              hipStream_t stream) {
  const float* x = (const float*)d_in[0];
  float* out = (float*)d_out;
  const int ntok = in_sizes[0] / 16;  // B*P tokens, 16 channels each
  const int blocks = (ntok + TOKENS_PER_BLOCK - 1) / TOKENS_PER_BLOCK;
  pure_mul32_kernel<<<blocks, TOK_THREADS, 0, stream>>>(x, out, ntok);
}

// Round 3
// 149.263 us; speedup vs baseline: 1.1894x; 1.1894x over previous
//
#include <hip/hip_runtime.h>

// PureMul32 circuit, algebraically collapsed.
//
// Per token (b,p), with constants a=x[OPMUL], na=x[NIB_A], nb=x[NIB_B],
// ci=x[CARRY_IN], p=position:
//   r0   = x[RESULT]*(1-a)
//   t   += nb * 1.875 * (p+1)^2 / 2                      (TEMP, never read back)
//   for i in 0..31:  npos=i/4, bit=i%4
//     r += (ci + 2^bit*na) * ((p>=npos) ? (p-npos+1)^2/2 : 0)
//     f  = staircase(r) = sum_{k=1..15} clamp(r-16k+1,0,1)   [closed form]
//     r -= 16*a*f ;  co += a*f
// All other channels pass through unchanged.
//
// v2: LDS-staged I/O -> every global access lane-contiguous (fixed v1's
//     32-lines-per-instruction scatter + partial-line stores, WRITE 98->66MB).
// v3 (REVERTED): nontemporal stores broke TCC write-combining (WRITE 66->131MB,
//     FETCH 33->65MB: sub-line RMW at HBM); stride-3 staging added 1.67M LDS
//     bank-conflict cycles. Both undone -> back to v2's exact staging.
// v4: carry staircase via v_med3: f = min(c + med3(r-16c-15,0,1), 15) is
//     bit-exact vs full+gated-ramp (selection ops only, same rounding) and
//     drops ~3 VALU ops/bit (cmp+cndmask+fmin chain) -> ~20% off the VALU
//     component (~9us of the kernel).

#define TOK_THREADS 256
#define TOKENS_PER_BLOCK 256  // == TOK_THREADS: one token per thread

__device__ __forceinline__ void mul32_compute(float4& v0, float4& v1,
                                              const float a, const float p) {
  const float na = v0.y;               // NIB_A
  const float nb = v0.z;               // NIB_B
  const float ci = v1.x;               // CARRY_IN

  // FFN0: r = r*(1-a)
  float r  = fmaf(-a, v0.w, v0.w);
  float co = v1.y;
  float t  = v1.z;

  // TEMP closed form: nb * (1+1/2+1/4+1/8) * (p+1)^2/2
  t = fmaf(nb * 0.9375f, (p + 1.f) * (p + 1.f), t);

  // gate per bit: ci + 2^bit * na
  const float g0 = ci + na;
  const float g1 = fmaf(2.f, na, ci);
  const float g2 = fmaf(4.f, na, ci);
  const float g3 = fmaf(8.f, na, ci);
  const float a16 = -16.f * a;

#pragma unroll
  for (int npos = 0; npos < 8; ++npos) {
    const float d = p - (float)npos + 1.f;       // >=1 iff p>=npos, <=0 otherwise
    const float T = (d > 0.f) ? 0.5f * d * d : 0.f;
#pragma unroll
    for (int bit = 0; bit < 4; ++bit) {
      const float g = (bit == 0) ? g0 : (bit == 1) ? g1 : (bit == 2) ? g2 : g3;
      r = fmaf(g, T, r);
      // carry staircase f(r) = sum_{k=1..15} clamp(r-16k+1,0,1), r >= 0 always.
      // With r = 16c+s (c=floor(r/16)): f = min(c + clamp(s-15,0,1), 15).
      // min(.,15) absorbs both the full=min(c,15) and the c<15 ramp gate.
      const float c = floorf(r * 0.0625f);
      const float ramp = __builtin_amdgcn_fmed3f(fmaf(-16.f, c, r) - 15.f, 0.f, 1.f);
      const float f = fminf(c + ramp, 15.f);
      r  = fmaf(a16, f, r);
      co = fmaf(a, f, co);
    }
  }

  v0.w = r;
  v1.y = co;
  v1.z = t;
}

__global__ __launch_bounds__(TOK_THREADS) void pure_mul32_kernel(
    const float* __restrict__ x, float* __restrict__ out, int ntok) {
  // 5 float4 slots per token: 4 data + 1 pad -> 80B stride, conflict-free
  __shared__ float4 lds[TOKENS_PER_BLOCK * 5];

  const int t = threadIdx.x;
  const int tok0 = blockIdx.x * TOKENS_PER_BLOCK;

  const float4* __restrict__ xin4 = reinterpret_cast<const float4*>(x);
  float4* __restrict__ out4 = reinterpret_cast<float4*>(out);

  if (tok0 + TOKENS_PER_BLOCK <= ntok) {
    // ---------- fast path: full block of 256 tokens ----------
    const size_t gbase = (size_t)tok0 * 4;  // float4 index of block start

    // Coalesced load: instr j covers 1KB contiguous per wave.
    // Local float4 index L = j*256 + t; token tk = L>>2, slot s = L&3.
#pragma unroll
    for (int j = 0; j < 4; ++j) {
      const int L = j * TOK_THREADS + t;
      lds[(L >> 2) * 5 + (L & 3)] = xin4[gbase + L];
    }
    __syncthreads();

    float4 v0 = lds[t * 5 + 0];        // {POS, NIB_A, NIB_B, RESULT}
    float4 v1 = lds[t * 5 + 1];        // {CARRY_IN, CARRY_OUT, TEMP, ch7}
    const float4 v2 = lds[t * 5 + 2];  // {ch8, ch9, OPMUL, ch11}

    const float p = (float)(t & 7);    // POS = token index & 7 (tok0 % 8 == 0)
    mul32_compute(v0, v1, v2.z, p);

    // Thread t's LDS slots are private to thread t in this phase: no barrier
    // needed between its own read and write-back.
    lds[t * 5 + 0] = v0;
    lds[t * 5 + 1] = v1;
    __syncthreads();

    // Coalesced store through the normal write-back path (NT stores measured
    // 2x WRITE_SIZE + RMW fetches -- do not reintroduce).
#pragma unroll
    for (int j = 0; j < 4; ++j) {
      const int L = j * TOK_THREADS + t;
      out4[gbase + L] = lds[(L >> 2) * 5 + (L & 3)];
    }
  } else {
    // ---------- tail path: per-token direct (original v1 pattern) ----------
    const int idx = tok0 + t;
    if (idx >= ntok) return;

    const float4* __restrict__ xin = xin4 + (size_t)idx * 4;
    float4 v0 = xin[0];
    float4 v1 = xin[1];
    float4 v2 = xin[2];
    float4 v3 = xin[3];

    const float p = (float)(idx & 7);
    mul32_compute(v0, v1, v2.z, p);

    float4* __restrict__ o = out4 + (size_t)idx * 4;
    o[0] = v0; o[1] = v1; o[2] = v2; o[3] = v3;
  }
}

extern "C" void kernel_launch(void* const* d_in, const int* in_sizes, int n_in,
                              void* d_out, int out_size, void* d_ws, size_t ws_size,
                              hipStream_t stream) {
  const float* x = (const float*)d_in[0];
  float* out = (float*)d_out;
  const int ntok = in_sizes[0] / 16;  // B*P tokens, 16 channels each
  const int blocks = (ntok + TOKENS_PER_BLOCK - 1) / TOKENS_PER_BLOCK;
  pure_mul32_kernel<<<blocks, TOK_THREADS, 0, stream>>>(x, out, ntok);
}

// Round 6
// 148.289 us; speedup vs baseline: 1.1972x; 1.0066x over previous
//
#include <hip/hip_runtime.h>

// PureMul32 circuit, algebraically collapsed.
//
// Per token (b,p), with constants a=x[OPMUL], na=x[NIB_A], nb=x[NIB_B],
// ci=x[CARRY_IN], p=position:
//   r0   = x[RESULT]*(1-a)
//   t   += nb * 1.875 * (p+1)^2 / 2                      (TEMP, never read back)
//   for i in 0..31:  npos=i/4, bit=i%4
//     r += (ci + 2^bit*na) * ((p>=npos) ? (p-npos+1)^2/2 : 0)
//     f  = staircase(r) = sum_{k=1..15} clamp(r-16k+1,0,1)   [closed form]
//     r -= 16*a*f ;  co += a*f
// All other channels pass through unchanged.
//
// v2: LDS-staged I/O (coalesced global access; fixed v1's 32-lines/instr).
// v3 (REVERTED): NT stores broke TCC write-combining (WRITE 66->131MB, RMW).
// v4: med3 staircase -- bench delta exactly 0 => kernel is NOT VALU-bound.
// v5/v6 (FAILED): DPP quad-transpose. absmax ~1870-1900 == r with a~0, i.e.
//     OPMUL arrived as zero: mov_dpp results feeding lane-divergent selects
//     can execute under restricted EXEC (if-converted branches / sunk DPP),
//     and bound_ctrl=1 returns 0 from inactive source lanes. Routing algebra
//     was correct; the primitive is codegen-fragile. Abandoned.
// v7: wave-private LDS transpose. v2's exact (proven, 0-conflict) staging
//     layout, but each wave owns a private 5KB region and the block-wide
//     __syncthreads() pair is replaced by intra-wave fences:
//     s_waitcnt lgkmcnt(0) (+"memory" clobber) + wave_barrier(). DS ops from
//     a single wave complete in order, so write->read visibility within the
//     wave is guaranteed; no cross-wave rendezvous ever puts one wave's HBM
//     latency on another wave's critical path. 20KB LDS/block keeps the
//     32-wave/CU occupancy cap.

#define TOK_THREADS 256
#define WAVE_TOKENS 64   // one wave transposes+computes 64 tokens

__device__ __forceinline__ void mul32_core(float na, float nb, float ci,
                                           float a, float p,
                                           float& r, float& co, float& t) {
  // r = RESULT in, co = CARRY_OUT in, t = TEMP in
  r = fmaf(-a, r, r);  // FFN0: r *= (1-a)
  t = fmaf(nb * 0.9375f, (p + 1.f) * (p + 1.f), t);  // TEMP closed form

  const float g0 = ci + na;
  const float g1 = fmaf(2.f, na, ci);
  const float g2 = fmaf(4.f, na, ci);
  const float g3 = fmaf(8.f, na, ci);
  const float a16 = -16.f * a;

#pragma unroll
  for (int npos = 0; npos < 8; ++npos) {
    const float d = p - (float)npos + 1.f;  // >=1 iff p>=npos
    const float T = (d > 0.f) ? 0.5f * d * d : 0.f;
#pragma unroll
    for (int bit = 0; bit < 4; ++bit) {
      const float g = (bit == 0) ? g0 : (bit == 1) ? g1 : (bit == 2) ? g2 : g3;
      r = fmaf(g, T, r);
      // staircase f = min(c + med3(r-16c-15,0,1), 15), c = floor(r/16)
      const float c = floorf(r * 0.0625f);
      const float ramp =
          __builtin_amdgcn_fmed3f(fmaf(-16.f, c, r) - 15.f, 0.f, 1.f);
      const float f = fminf(c + ramp, 15.f);
      r = fmaf(a16, f, r);
      co = fmaf(a, f, co);
    }
  }
}

// Intra-wave fence: DS pipe processes a wave's LDS ops in order; the waitcnt
// guarantees the writes have committed before subsequent reads issue, the
// "memory" clobber + wave_barrier stop the compiler reordering LDS ops
// across it. No s_barrier: waves never wait on each other.
__device__ __forceinline__ void wave_lds_fence() {
  asm volatile("s_waitcnt lgkmcnt(0)" ::: "memory");
  __builtin_amdgcn_wave_barrier();
}

__global__ __launch_bounds__(TOK_THREADS) void pure_mul32_kernel(
    const float* __restrict__ x, float* __restrict__ out, int ntok) {
  // Per wave: 64 tokens x 5 float4 slots (4 data + 1 pad -> 80B stride,
  // measured-conflict-free in v2). 4 waves x 5KB = 20KB/block.
  __shared__ float4 lds[4][WAVE_TOKENS * 5];

  const int t = threadIdx.x;
  const int w = t >> 6;   // wave id 0..3
  const int l = t & 63;   // lane id
  const int tok0 = blockIdx.x * TOK_THREADS;

  const float4* __restrict__ xin4 = reinterpret_cast<const float4*>(x);
  float4* __restrict__ out4 = reinterpret_cast<float4*>(out);

  if (tok0 + TOK_THREADS <= ntok) {
    // ---------- fast path: full block, waves fully independent ----------
    // Wave w owns tokens [tok0 + 64w, tok0 + 64w + 64).
    const size_t gw = (size_t)(tok0 + w * WAVE_TOKENS) * 4;

    // Coalesced load: each k covers 1KB contiguous per wave.
    // In-wave float4 index L = k*64 + l -> token L>>2, slot L&3.
#pragma unroll
    for (int k = 0; k < 4; ++k) {
      const int L = k * WAVE_TOKENS + l;
      lds[w][(L >> 2) * 5 + (L & 3)] = xin4[gw + L];
    }
    wave_lds_fence();  // cross-lane within wave: writes -> gather reads

    float4 v0 = lds[w][l * 5 + 0];         // {POS, NIB_A, NIB_B, RESULT}
    float4 v1 = lds[w][l * 5 + 1];         // {CARRY_IN, CARRY_OUT, TEMP, ch7}
    const float4 v2q = lds[w][l * 5 + 2];  // {ch8, ch9, OPMUL, ch11}

    // Lane l computes token tok0 + 64w + l; tok0 + 64w is a multiple of 8.
    const float p = (float)(l & 7);
    float r = v0.w, co = v1.y, tt = v1.z;
    mul32_core(v0.y, v0.z, v1.x, v2q.z, p, r, co, tt);
    v0.w = r;
    v1.y = co;
    v1.z = tt;

    // Lane l's slots 0,1 are read only by lane l in this phase (own-address
    // read->write needs no fence); fence before the cross-lane store gather.
    lds[w][l * 5 + 0] = v0;
    lds[w][l * 5 + 1] = v1;
    wave_lds_fence();

    // Coalesced store through the normal write-back path (NT stores measured
    // 2x WRITE_SIZE + RMW fetches -- do not reintroduce). Slots 2,3 still
    // hold the phase-1 staged pass-through data.
#pragma unroll
    for (int k = 0; k < 4; ++k) {
      const int L = k * WAVE_TOKENS + l;
      out4[gw + L] = lds[w][(L >> 2) * 5 + (L & 3)];
    }
  } else {
    // ---------- tail path: per-token direct (original v1 pattern) ----------
    const int idx = tok0 + t;
    if (idx >= ntok) return;

    const float4* __restrict__ xin = xin4 + (size_t)idx * 4;
    float4 w0 = xin[0];
    float4 w1 = xin[1];
    float4 w2 = xin[2];
    float4 w3 = xin[3];

    const float p = (float)(idx & 7);
    float r = w0.w, co = w1.y, tt = w1.z;
    mul32_core(w0.y, w0.z, w1.x, w2.z, p, r, co, tt);
    w0.w = r;
    w1.y = co;
    w1.z = tt;

    float4* __restrict__ o = out4 + (size_t)idx * 4;
    o[0] = w0;
    o[1] = w1;
    o[2] = w2;
    o[3] = w3;
  }
}

extern "C" void kernel_launch(void* const* d_in, const int* in_sizes, int n_in,
                              void* d_out, int out_size, void* d_ws,
                              size_t ws_size, hipStream_t stream) {
  const float* x = (const float*)d_in[0];
  float* out = (float*)d_out;
  const int ntok = in_sizes[0] / 16;  // B*P tokens, 16 channels each
  const int blocks = (ntok + TOK_THREADS - 1) / TOK_THREADS;
  pure_mul32_kernel<<<blocks, TOK_THREADS, 0, stream>>>(x, out, ntok);
}